// Round 7
// baseline (572.736 us; speedup 1.0000x reference)
//
#include <hip/hip_runtime.h>
#include <cstdint>

// FP32 external interface (reference is jnp.float32). Intermediates bf16 (u16),
// all accumulation fp32. R12: non-conv restructure. k_build split: x2-transpose
// (comb-lo) merged into k_reduce's launch as a block-range path; y-gather
// (comb-hi) is now one-thread-per-particle with zero barriers (800K independent
// uidx->sidx->y chains, TLP-hidden). k_prep grid-strided. Convs untouched
// (at the random-line-service roofline, ~130us each).

typedef unsigned short u16;
typedef u16 u16x8 __attribute__((ext_vector_type(8)));
typedef float f4 __attribute__((ext_vector_type(4)));
using s16x8 = __attribute__((ext_vector_type(8))) short;
using u16x4 = __attribute__((ext_vector_type(4))) u16;

#define EPS 1e-5f
#define BB 2
#define CIN 64
#define CH 32
#define SVOX 64000
#define NC 100000
#define NF 400000

static __device__ __forceinline__ float b2f(u16 h) {
    return __builtin_bit_cast(float, (unsigned)h << 16);
}
static __device__ __forceinline__ u16 f2b(float f) {
    unsigned u = __builtin_bit_cast(unsigned, f);
    u += 0x7FFFu + ((u >> 16) & 1u);
    return (u16)(u >> 16);
}
static __device__ __forceinline__ f4 mfma16(s16x8 a, s16x8 b, f4 c) {
    return __builtin_amdgcn_mfma_f32_16x16x32_bf16(a, b, c, 0, 0, 0);
}

// ---------------- prep: zero stats + build MFMA A-fragment weight tables -------
__global__ __launch_bounds__(256) void k_prep(
    const float* __restrict__ w1, const float* __restrict__ w2,
    float* __restrict__ stats, u16* __restrict__ wf1, u16* __restrict__ wf2)
{
    int t0 = blockIdx.x * 256 + threadIdx.x, stride = gridDim.x * 256;
    for (int i = t0; i < 12288; i += stride) stats[i] = 0.f;
    for (int i = t0; i < 14 * 2 * 512; i += stride) {
        int j = i & 7, l = (i >> 3) & 63, ot = (i >> 9) & 1, s = i >> 10;
        int k = s >> 1, h = s & 1;
        int c = h * 32 + (l >> 4) * 8 + j;
        int o = ot * 16 + (l & 15);
        wf1[i] = f2b(w1[(o * CIN + c) * 7 + k]);
    }
    for (int i = t0; i < 7 * 2 * 512; i += stride) {
        int j = i & 7, l = (i >> 3) & 63, ot = (i >> 9) & 1, k = i >> 10;
        int c = (l >> 4) * 8 + j;
        int o = ot * 16 + (l & 15);
        wf2[i] = f2b(w2[(o * CH + c) * 7 + k]);
    }
}

// ---------------- merged: dense 1x1x1 conv + GN-A stats  ||  x2 -> comb-lo ------
// blockIdx.x < 125: reduce path (unchanged). Else: streaming transpose of x2
// f32 [B][32][NF] into the low 64-B half of comb records (no normalization).
__global__ __launch_bounds__(256) void k_rb(
    const float* __restrict__ x1, const float* __restrict__ wr,
    const float* __restrict__ x2, u16* __restrict__ y,
    float* __restrict__ statsA, u16* __restrict__ comb)
{
    __shared__ float wl[CIN * CH];
    __shared__ float sred[64];
    __shared__ u16 tile[64][40];
    int tid = threadIdx.x, b = blockIdx.y, bx = blockIdx.x;
    if (bx < 125) {
        // ---- reduce path ----
        if (tid < 64) sred[tid] = 0.f;
        for (int i = tid; i < CIN * CH; i += 256) {
            int c = i >> 5, o = i & 31;
            wl[i] = wr[o * CIN + c];   // wl[c][o]
        }
        __syncthreads();
        int s0 = bx * 512 + tid;
        int s1 = s0 + 256;
        const float* xb = x1 + (size_t)b * CIN * SVOX;
        float acc0[CH], acc1[CH];
#pragma unroll
        for (int o = 0; o < CH; o++) { acc0[o] = 0.f; acc1[o] = 0.f; }
        for (int c = 0; c < CIN; c++) {
            float xv0 = xb[(size_t)c * SVOX + s0];
            float xv1 = xb[(size_t)c * SVOX + s1];
            const float* w = &wl[c * CH];
#pragma unroll
            for (int o = 0; o < CH; o++) {
                float wv = w[o];
                acc0[o] = fmaf(xv0, wv, acc0[o]);
                acc1[o] = fmaf(xv1, wv, acc1[o]);
            }
        }
        u16* y0 = y + ((size_t)b * SVOX + s0) * CH;
        u16* y1 = y + ((size_t)b * SVOX + s1) * CH;
#pragma unroll
        for (int g = 0; g < 4; g++) {
            u16x8 v0, v1;
#pragma unroll
            for (int i = 0; i < 8; i++) {
                v0[i] = f2b(acc0[g * 8 + i]);
                v1[i] = f2b(acc1[g * 8 + i]);
            }
            ((u16x8*)y0)[g] = v0;
            ((u16x8*)y1)[g] = v1;
        }
        int lane = tid & 63;
#pragma unroll
        for (int g = 0; g < 4; g++) {
            float s[8], qq[8];
#pragma unroll
            for (int i = 0; i < 8; i++) {
                int o = g * 8 + i;
                s[i] = acc0[o] + acc1[o];
                qq[i] = fmaf(acc0[o], acc0[o], acc1[o] * acc1[o]);
            }
#pragma unroll
            for (int m = 1; m < 64; m <<= 1) {
#pragma unroll
                for (int i = 0; i < 8; i++) {
                    s[i] += __shfl_xor(s[i], m);
                    qq[i] += __shfl_xor(qq[i], m);
                }
            }
            if (lane == 0) {
#pragma unroll
                for (int i = 0; i < 8; i++) {
                    atomicAdd(&sred[(g * 8 + i) * 2], s[i]);
                    atomicAdd(&sred[(g * 8 + i) * 2 + 1], qq[i]);
                }
            }
        }
        __syncthreads();
        if (tid < 64) atomicAdd(&statsA[(size_t)(b * 64 + tid) * 32], sred[tid]);
    } else {
        // ---- build-lo path: transpose 64-particle tiles, all 256 threads ----
        int c = tid >> 3, no = (tid & 7) * 8;
        int nl2 = tid >> 2, sg = tid & 3;
        int nblk = gridDim.x - 125;
        for (int t = bx - 125; t < 6250; t += nblk) {
            int n0 = t * 64;
            const float* src = x2 + ((size_t)b * CH + c) * NF + n0 + no;
            f4 v0 = *(const f4*)src;
            f4 v1 = *(const f4*)(src + 4);
            __syncthreads();   // previous iteration's readers done
#pragma unroll
            for (int i = 0; i < 4; i++) tile[no + i][c] = f2b(v0[i]);
#pragma unroll
            for (int i = 0; i < 4; i++) tile[no + 4 + i][c] = f2b(v1[i]);
            __syncthreads();
            u16x8 ov;
#pragma unroll
            for (int i = 0; i < 8; i++) ov[i] = tile[nl2][sg * 8 + i];
            *(u16x8*)(comb + ((size_t)b * NF + n0 + nl2) * 64 + sg * 8) = ov;
        }
    }
}

// ---------------- comb-hi: per-particle gather chain, barrier-free --------------
// comb[n][32..63] = relu(norm(y[sidx[uidx[n]]])). One thread per particle,
// 800K independent uidx->sidx->y chains; latency hidden by TLP.
__global__ __launch_bounds__(256) void k_bhi(
    const u16* __restrict__ y, const float* __restrict__ statsA,
    const float* __restrict__ gA, const float* __restrict__ bA,
    const int* __restrict__ sidx, const int* __restrict__ uidx,
    u16* __restrict__ comb)
{
    __shared__ float sl[BB][64];
    int tid = threadIdx.x;
    if (tid < BB * CH) {
        int b = tid >> 5, c = tid & 31;
        float sum = statsA[(size_t)(b * 64 + c * 2) * 32];
        float sq  = statsA[(size_t)(b * 64 + c * 2 + 1) * 32];
        float mean = sum * (1.f / SVOX);
        float var = sq * (1.f / SVOX) - mean * mean;
        float s = rsqrtf(var + EPS) * gA[c];
        sl[b][c * 2] = s;
        sl[b][c * 2 + 1] = bA[c] - mean * s;
    }
    __syncthreads();
    for (int idx = blockIdx.x * 256 + tid; idx < BB * NF; idx += gridDim.x * 256) {
        int b = (idx >= NF) ? 1 : 0;
        int u = uidx[idx];
        int j = sidx[(size_t)b * NC + u];
        const u16x8* yr = (const u16x8*)(y + ((size_t)b * SVOX + j) * CH);
        u16* dst = comb + (size_t)idx * 64 + 32;
        const float* slb = sl[b];
#pragma unroll
        for (int g = 0; g < 4; g++) {
            u16x8 v = yr[g];
            u16x8 ov;
#pragma unroll
            for (int i = 0; i < 8; i++) {
                int c = g * 8 + i;
                ov[i] = f2b(fmaxf(fmaf(b2f(v[i]), slb[c * 2], slb[c * 2 + 1]), 0.f));
            }
            *(u16x8*)(dst + g * 8) = ov;
        }
    }
}

// ---------------- conv1: MFMA gather-GEMM over 128-B comb records ---------------
// out[n][o] = sum_{k,c} comb[nbr[n][k]][c] * w1[o][c][k]; fused stats1.
__global__ __launch_bounds__(512) void k_conv1(
    const u16* __restrict__ comb, const u16* __restrict__ wfg,
    const int* __restrict__ nbr, u16* __restrict__ h1,
    float* __restrict__ stats1)
{
    __shared__ u16 wf[14 * 2 * 512];   // 28 KB shared by 8 waves
    __shared__ float sst[64];
    int tid = threadIdx.x, b = blockIdx.y;
    if (tid < 64) sst[tid] = 0.f;
    const f4* wsrc = (const f4*)wfg;
    f4* wdst = (f4*)wf;
    for (int i = tid; i < 1792; i += 512) wdst[i] = wsrc[i];
    __syncthreads();
    const s16x8* wfv = (const s16x8*)wf;
    int lane = tid & 63, wave = tid >> 6;
    int p = lane & 15, q = lane >> 4;
    int n = blockIdx.x * 128 + wave * 16 + p;   // grid exact: 3125*128 == NF
    const u16* Cb = comb + (size_t)b * NF * 64;
    const int* nbb = nbr + ((size_t)b * NF + n) * 7;
    int i0[7];
#pragma unroll
    for (int k = 0; k < 7; k++) i0[k] = nbb[k];
    s16x8 rlo[7], rhi[7];
#pragma unroll
    for (int k = 0; k < 7; k++) {
        const u16* rec = Cb + (size_t)i0[k] * 64;
        rlo[k] = __builtin_bit_cast(s16x8, *(const u16x8*)(rec + q * 8));
        rhi[k] = __builtin_bit_cast(s16x8, *(const u16x8*)(rec + 32 + q * 8));
    }
    f4 acc0 = {0.f, 0.f, 0.f, 0.f};
    f4 acc1 = {0.f, 0.f, 0.f, 0.f};
#pragma unroll
    for (int k = 0; k < 7; k++) {
        acc0 = mfma16(wfv[(k * 4 + 0) * 64 + lane], rlo[k], acc0);
        acc1 = mfma16(wfv[(k * 4 + 1) * 64 + lane], rlo[k], acc1);
        acc0 = mfma16(wfv[(k * 4 + 2) * 64 + lane], rhi[k], acc0);
        acc1 = mfma16(wfv[(k * 4 + 3) * 64 + lane], rhi[k], acc1);
    }
    // fused stats: reduce over the 16 particles (p) per channel, f32 pre-rounding
    float s[8], t[8];
#pragma unroll
    for (int r = 0; r < 4; r++) {
        s[r] = acc0[r];     t[r] = acc0[r] * acc0[r];
        s[4 + r] = acc1[r]; t[4 + r] = acc1[r] * acc1[r];
    }
#pragma unroll
    for (int m = 1; m < 16; m <<= 1) {
#pragma unroll
        for (int j = 0; j < 8; j++) {
            s[j] += __shfl_xor(s[j], m);
            t[j] += __shfl_xor(t[j], m);
        }
    }
    if (p == 0) {
#pragma unroll
        for (int r = 0; r < 4; r++) {
            atomicAdd(&sst[(q * 4 + r) * 2],       s[r]);
            atomicAdd(&sst[(q * 4 + r) * 2 + 1],   t[r]);
            atomicAdd(&sst[(16 + q * 4 + r) * 2],     s[4 + r]);
            atomicAdd(&sst[(16 + q * 4 + r) * 2 + 1], t[4 + r]);
        }
    }
    // D: col = lane&15 = particle, row = 4*q + r = output channel
    u16x4 v0, v1;
#pragma unroll
    for (int r = 0; r < 4; r++) { v0[r] = f2b(acc0[r]); v1[r] = f2b(acc1[r]); }
    u16* out = h1 + ((size_t)b * NF + n) * CH + q * 4;
    *(u16x4*)out = v0;
    *(u16x4*)(out + 16) = v1;
    __syncthreads();
    if (tid < 64) atomicAdd(&stats1[(size_t)(b * 64 + tid) * 32], sst[tid]);
}

// ---------------- conv2: gather-GEMM, fin1+norm1+relu fused, f32 out ------------
// GN-1 finalize computed per-lane in registers (no serial wave-0 head).
__global__ __launch_bounds__(512) void k_conv2(
    const u16* __restrict__ x, const u16* __restrict__ wfg,
    const int* __restrict__ nbr, const float* __restrict__ stats1,
    const float* __restrict__ g1, const float* __restrict__ b1,
    float* __restrict__ out, float* __restrict__ stats2)
{
    __shared__ u16 wf[7 * 2 * 512];   // 14 KB shared by 8 waves
    __shared__ float sst[64];
    int tid = threadIdx.x, b = blockIdx.y;
    if (tid < 64) sst[tid] = 0.f;
    const f4* wsrc = (const f4*)wfg;
    f4* wdst = (f4*)wf;
    for (int i = tid; i < 896; i += 512) wdst[i] = wsrc[i];
    __syncthreads();
    const s16x8* wfv = (const s16x8*)wf;
    int lane = tid & 63, wave = tid >> 6;
    int p = lane & 15, q = lane >> 4;
    int n = blockIdx.x * 128 + wave * 16 + p;
    const u16* Xb = x + (size_t)b * NF * CH;
    const int* nbb = nbr + ((size_t)b * NF + n) * 7;
    int i0[7];
#pragma unroll
    for (int k = 0; k < 7; k++) i0[k] = nbb[k];
    // per-lane GN-1 finalize for this lane's 8 channels (L2-broadcast loads)
    float sc[8], sh[8];
#pragma unroll
    for (int j = 0; j < 8; j++) {
        int ch = q * 8 + j;
        float sum = stats1[(size_t)(b * 64 + ch * 2) * 32];
        float sq  = stats1[(size_t)(b * 64 + ch * 2 + 1) * 32];
        float mean = sum * (1.f / NF);
        float var = sq * (1.f / NF) - mean * mean;
        float s = rsqrtf(var + EPS) * g1[ch];
        sc[j] = s;
        sh[j] = b1[ch] - mean * s;
    }
    u16x8 raw[7];
#pragma unroll
    for (int k = 0; k < 7; k++)
        raw[k] = *(const u16x8*)(Xb + (size_t)i0[k] * CH + q * 8);
    f4 acc0 = {0.f, 0.f, 0.f, 0.f};
    f4 acc1 = {0.f, 0.f, 0.f, 0.f};
#pragma unroll
    for (int k = 0; k < 7; k++) {
        u16x8 nv;
#pragma unroll
        for (int j = 0; j < 8; j++)
            nv[j] = f2b(fmaxf(fmaf(b2f(raw[k][j]), sc[j], sh[j]), 0.f));
        s16x8 a = __builtin_bit_cast(s16x8, nv);
        acc0 = mfma16(wfv[(k * 2 + 0) * 64 + lane], a, acc0);
        acc1 = mfma16(wfv[(k * 2 + 1) * 64 + lane], a, acc1);
    }
    // fused stats2 on raw f32 conv output
    float s[8], t[8];
#pragma unroll
    for (int r = 0; r < 4; r++) {
        s[r] = acc0[r];     t[r] = acc0[r] * acc0[r];
        s[4 + r] = acc1[r]; t[4 + r] = acc1[r] * acc1[r];
    }
#pragma unroll
    for (int m = 1; m < 16; m <<= 1) {
#pragma unroll
        for (int j = 0; j < 8; j++) {
            s[j] += __shfl_xor(s[j], m);
            t[j] += __shfl_xor(t[j], m);
        }
    }
    if (p == 0) {
#pragma unroll
        for (int r = 0; r < 4; r++) {
            atomicAdd(&sst[(q * 4 + r) * 2],       s[r]);
            atomicAdd(&sst[(q * 4 + r) * 2 + 1],   t[r]);
            atomicAdd(&sst[(16 + q * 4 + r) * 2],     s[4 + r]);
            atomicAdd(&sst[(16 + q * 4 + r) * 2 + 1], t[4 + r]);
        }
    }
    // f32 transposed store: out[b][ch][n]
    float* ob = out + (size_t)b * CH * NF + n;
#pragma unroll
    for (int r = 0; r < 4; r++) {
        ob[(size_t)(q * 4 + r) * NF] = acc0[r];
        ob[(size_t)(16 + q * 4 + r) * NF] = acc1[r];
    }
    __syncthreads();
    if (tid < 64) atomicAdd(&stats2[(size_t)(b * 64 + tid) * 32], sst[tid]);
}

// ---------------- in-place fin2+normalize+relu on f32 [B][32][NF] ---------------
__global__ __launch_bounds__(256) void k_norm2c(
    float* __restrict__ h, const float* __restrict__ stats2,
    const float* __restrict__ g2, const float* __restrict__ b2)
{
    const int total = BB * CH * (NF / 4);   // 6,400,000 f4 elements
    for (int i4 = blockIdx.x * 256 + threadIdx.x; i4 < total; i4 += gridDim.x * 256) {
        int cf = i4 / (NF / 4);              // 0..63 = b*32 + c
        int o = cf & 31;
        float sum = stats2[(size_t)(cf * 2) * 32];
        float sq  = stats2[(size_t)(cf * 2 + 1) * 32];
        float mean = sum * (1.f / NF);
        float var = sq * (1.f / NF) - mean * mean;
        float sc = rsqrtf(var + EPS) * g2[o];
        float sh = b2[o] - mean * sc;
        f4 v = ((f4*)h)[i4];
#pragma unroll
        for (int j = 0; j < 4; j++) v[j] = fmaxf(fmaf(v[j], sc, sh), 0.f);
        ((f4*)h)[i4] = v;
    }
}

extern "C" void kernel_launch(void* const* d_in, const int* in_sizes, int n_in,
                              void* d_out, int out_size, void* d_ws, size_t ws_size,
                              hipStream_t stream)
{
    const float* x1 = (const float*)d_in[0];
    const float* x2 = (const float*)d_in[1];
    const float* wr = (const float*)d_in[2];
    const float* gA = (const float*)d_in[3];
    const float* bA = (const float*)d_in[4];
    const float* w1 = (const float*)d_in[5];
    const float* g1 = (const float*)d_in[6];
    const float* b1 = (const float*)d_in[7];
    const float* w2 = (const float*)d_in[8];
    const float* g2 = (const float*)d_in[9];
    const float* b2 = (const float*)d_in[10];
    const int* sidx = (const int*)d_in[11];
    const int* uidx = (const int*)d_in[12];
    const int* nbr  = (const int*)d_in[13];

    // comb [B][NF][64] bf16 = 102.4 MB lives in d_out (dead before conv2 writes
    // f32 output there). ws (~59.5 MB): h1 51.2 | y 8.19 | stats | wf tables.
    char* ws = (char*)d_ws;
    u16* h1      = (u16*)ws;                            // [B][NF][32] bf16
    u16* y       = (u16*)(ws + 51200000);               // [B][SVOX][32] bf16
    float* stats = (float*)(ws + 59392000);             // 3 x 16 KB padded accumulators
    float* statsA = stats;
    float* stats1 = (float*)(ws + 59392000 + 16384);
    float* stats2 = (float*)(ws + 59392000 + 32768);
    u16* wf1g = (u16*)(ws + 59392000 + 49152);          // 28672 B
    u16* wf2g = (u16*)(ws + 59392000 + 49152 + 28672);  // 14336 B
    u16* comb = (u16*)d_out;

    k_prep<<<48, 256, 0, stream>>>(w1, w2, stats, wf1g, wf2g);
    k_rb<<<dim3(1149, BB), 256, 0, stream>>>(x1, wr, x2, y, statsA, comb);
    k_bhi<<<2048, 256, 0, stream>>>(y, statsA, gA, bA, sidx, uidx, comb);
    k_conv1<<<dim3(3125, BB), 512, 0, stream>>>(comb, wf1g, nbr, h1, stats1);
    k_conv2<<<dim3(3125, BB), 512, 0, stream>>>(h1, wf2g, nbr, stats1, g1, b1, (float*)d_out, stats2);
    k_norm2c<<<2048, 256, 0, stream>>>((float*)d_out, stats2, g2, b2);
}

// Round 8
// 545.315 us; speedup vs baseline: 1.0503x; 1.0503x over previous
//
#include <hip/hip_runtime.h>
#include <cstdint>

// FP32 external interface (reference is jnp.float32). Intermediates bf16 (u16),
// all accumulation fp32. R13: revert R12's k_build split (wrote 128-B records as
// 2x64-B halves across kernels -> regression). Back to R11 structure, plus
// NON-TEMPORAL hints on every zero-reuse stream (conv1 h1-stores, conv2
// f32-out stores, nbr loads, x1/x2 loads, norm2c) so the 256-MB L3 retains the
// random-gather pools (comb/h1). conv1's FETCH was 339 MB vs 125 MB cold-miss
// ideal -- streaming write-allocation was evicting the gather pool.

typedef unsigned short u16;
typedef u16 u16x8 __attribute__((ext_vector_type(8)));
typedef float f4 __attribute__((ext_vector_type(4)));
using s16x8 = __attribute__((ext_vector_type(8))) short;
using u16x4 = __attribute__((ext_vector_type(4))) u16;

#define EPS 1e-5f
#define BB 2
#define CIN 64
#define CH 32
#define SVOX 64000
#define NC 100000
#define NF 400000

static __device__ __forceinline__ float b2f(u16 h) {
    return __builtin_bit_cast(float, (unsigned)h << 16);
}
static __device__ __forceinline__ u16 f2b(float f) {
    unsigned u = __builtin_bit_cast(unsigned, f);
    u += 0x7FFFu + ((u >> 16) & 1u);
    return (u16)(u >> 16);
}
static __device__ __forceinline__ f4 mfma16(s16x8 a, s16x8 b, f4 c) {
    return __builtin_amdgcn_mfma_f32_16x16x32_bf16(a, b, c, 0, 0, 0);
}

// ---------------- prep: zero stats + build MFMA A-fragment weight tables -------
__global__ __launch_bounds__(256) void k_prep(
    const float* __restrict__ w1, const float* __restrict__ w2,
    float* __restrict__ stats, u16* __restrict__ wf1, u16* __restrict__ wf2)
{
    int t0 = blockIdx.x * 256 + threadIdx.x, stride = gridDim.x * 256;
    for (int i = t0; i < 12288; i += stride) stats[i] = 0.f;
    for (int i = t0; i < 14 * 2 * 512; i += stride) {
        int j = i & 7, l = (i >> 3) & 63, ot = (i >> 9) & 1, s = i >> 10;
        int k = s >> 1, h = s & 1;
        int c = h * 32 + (l >> 4) * 8 + j;
        int o = ot * 16 + (l & 15);
        wf1[i] = f2b(w1[(o * CIN + c) * 7 + k]);
    }
    for (int i = t0; i < 7 * 2 * 512; i += stride) {
        int j = i & 7, l = (i >> 3) & 63, ot = (i >> 9) & 1, k = i >> 10;
        int c = (l >> 4) * 8 + j;
        int o = ot * 16 + (l & 15);
        wf2[i] = f2b(w2[(o * CH + c) * 7 + k]);
    }
}

// ---------------- stage A: dense 1x1x1 conv (64 -> 32) + fused GN stats --------
__global__ __launch_bounds__(256) void k_reduce(
    const float* __restrict__ x1, const float* __restrict__ wr,
    u16* __restrict__ y, float* __restrict__ statsA)
{
    __shared__ float wl[CIN * CH];
    __shared__ float sred[64];
    int tid = threadIdx.x, b = blockIdx.y;
    if (tid < 64) sred[tid] = 0.f;
    for (int i = tid; i < CIN * CH; i += 256) {
        int c = i >> 5, o = i & 31;
        wl[i] = wr[o * CIN + c];   // wl[c][o]
    }
    __syncthreads();
    int s0 = blockIdx.x * 512 + tid;
    int s1 = s0 + 256;
    const float* xb = x1 + (size_t)b * CIN * SVOX;
    float acc0[CH], acc1[CH];
#pragma unroll
    for (int o = 0; o < CH; o++) { acc0[o] = 0.f; acc1[o] = 0.f; }
    for (int c = 0; c < CIN; c++) {
        float xv0 = __builtin_nontemporal_load(&xb[(size_t)c * SVOX + s0]);
        float xv1 = __builtin_nontemporal_load(&xb[(size_t)c * SVOX + s1]);
        const float* w = &wl[c * CH];
#pragma unroll
        for (int o = 0; o < CH; o++) {
            float wv = w[o];
            acc0[o] = fmaf(xv0, wv, acc0[o]);
            acc1[o] = fmaf(xv1, wv, acc1[o]);
        }
    }
    u16* y0 = y + ((size_t)b * SVOX + s0) * CH;
    u16* y1 = y + ((size_t)b * SVOX + s1) * CH;
#pragma unroll
    for (int g = 0; g < 4; g++) {
        u16x8 v0, v1;
#pragma unroll
        for (int i = 0; i < 8; i++) {
            v0[i] = f2b(acc0[g * 8 + i]);
            v1[i] = f2b(acc1[g * 8 + i]);
        }
        ((u16x8*)y0)[g] = v0;    // cacheable: k_build gathers y (8.2 MB pool)
        ((u16x8*)y1)[g] = v1;
    }
    // fused stats: wave butterfly per 8-channel group, then LDS + global atomics
    int lane = tid & 63;
#pragma unroll
    for (int g = 0; g < 4; g++) {
        float s[8], qq[8];
#pragma unroll
        for (int i = 0; i < 8; i++) {
            int o = g * 8 + i;
            s[i] = acc0[o] + acc1[o];
            qq[i] = fmaf(acc0[o], acc0[o], acc1[o] * acc1[o]);
        }
#pragma unroll
        for (int m = 1; m < 64; m <<= 1) {
#pragma unroll
            for (int i = 0; i < 8; i++) {
                s[i] += __shfl_xor(s[i], m);
                qq[i] += __shfl_xor(qq[i], m);
            }
        }
        if (lane == 0) {
#pragma unroll
            for (int i = 0; i < 8; i++) {
                atomicAdd(&sred[(g * 8 + i) * 2], s[i]);
                atomicAdd(&sred[(g * 8 + i) * 2 + 1], qq[i]);
            }
        }
    }
    __syncthreads();
    if (tid < 64) atomicAdd(&statsA[(size_t)(b * 64 + tid) * 32], sred[tid]);
}

// ---------------- build comb records [B][NF][64] bf16 (128 B each) -------------
// ch 0..31 = x2 (transposed), ch 32..63 = relu(norm(y[sidx[uidx[n]]])).
// Grid-stride over the 6250 64-particle tiles. comb stores stay cacheable:
// they seed L3 for conv1's random gathers.
__global__ __launch_bounds__(256) void k_build(
    const float* __restrict__ x2, const u16* __restrict__ y,
    const float* __restrict__ statsA, const float* __restrict__ gA,
    const float* __restrict__ bA, const int* __restrict__ sidx,
    const int* __restrict__ uidx, u16* __restrict__ comb)
{
    __shared__ u16 tile[64][40];
    __shared__ float sl[CH * 2];
    int tid = threadIdx.x, b = blockIdx.y;
    if (tid < CH) {
        float sum = statsA[(size_t)(b * 64 + tid * 2) * 32];
        float sq  = statsA[(size_t)(b * 64 + tid * 2 + 1) * 32];
        float mean = sum * (1.f / SVOX);
        float var = sq * (1.f / SVOX) - mean * mean;
        float sc = rsqrtf(var + EPS) * gA[tid];
        sl[tid * 2] = sc;
        sl[tid * 2 + 1] = bA[tid] - mean * sc;
    }
    int c = tid >> 3, no = (tid & 7) * 8;
    int nl = tid >> 3, seg = tid & 7;
    for (int t = blockIdx.x; t < 6250; t += gridDim.x) {
        int n0 = t * 64;
        const float* src = x2 + ((size_t)b * CH + c) * NF + n0 + no;
        f4 v0 = __builtin_nontemporal_load((const f4*)src);
        f4 v1 = __builtin_nontemporal_load((const f4*)(src + 4));
        __syncthreads();   // previous tile's phase-2 readers done (also: sl ready)
#pragma unroll
        for (int i = 0; i < 4; i++) tile[no + i][c] = f2b(v0[i]);
#pragma unroll
        for (int i = 0; i < 4; i++) tile[no + 4 + i][c] = f2b(v1[i]);
        __syncthreads();
#pragma unroll
        for (int it = 0; it < 2; it++) {
            int n = n0 + it * 32 + nl;
            u16x8 ov;
            if (seg < 4) {
                int co = seg * 8;
#pragma unroll
                for (int i = 0; i < 8; i++) ov[i] = tile[it * 32 + nl][co + i];
            } else {
                int u = uidx[(size_t)b * NF + n];
                int j = sidx[(size_t)b * NC + u];
                const u16x8* yr = (const u16x8*)(y + ((size_t)b * SVOX + j) * CH);
                u16x8 v = yr[seg - 4];
                int co = (seg - 4) * 8;
#pragma unroll
                for (int i = 0; i < 8; i++)
                    ov[i] = f2b(fmaxf(fmaf(b2f(v[i]), sl[(co + i) * 2], sl[(co + i) * 2 + 1]), 0.f));
            }
            *(u16x8*)(comb + ((size_t)b * NF + n) * 64 + seg * 8) = ov;
        }
    }
}

// ---------------- conv1: MFMA gather-GEMM over 128-B comb records ---------------
// out[n][o] = sum_{k,c} comb[nbr[n][k]][c] * w1[o][c][k]; fused stats1.
// h1 stores + nbr loads non-temporal: keep L3 for the comb gather pool.
__global__ __launch_bounds__(512) void k_conv1(
    const u16* __restrict__ comb, const u16* __restrict__ wfg,
    const int* __restrict__ nbr, u16* __restrict__ h1,
    float* __restrict__ stats1)
{
    __shared__ u16 wf[14 * 2 * 512];   // 28 KB shared by 8 waves
    __shared__ float sst[64];
    int tid = threadIdx.x, b = blockIdx.y;
    if (tid < 64) sst[tid] = 0.f;
    const f4* wsrc = (const f4*)wfg;
    f4* wdst = (f4*)wf;
    for (int i = tid; i < 1792; i += 512) wdst[i] = wsrc[i];
    __syncthreads();
    const s16x8* wfv = (const s16x8*)wf;
    int lane = tid & 63, wave = tid >> 6;
    int p = lane & 15, q = lane >> 4;
    int n = blockIdx.x * 128 + wave * 16 + p;   // grid exact: 3125*128 == NF
    const u16* Cb = comb + (size_t)b * NF * 64;
    const int* nbb = nbr + ((size_t)b * NF + n) * 7;
    int i0[7];
#pragma unroll
    for (int k = 0; k < 7; k++) i0[k] = __builtin_nontemporal_load(&nbb[k]);
    s16x8 rlo[7], rhi[7];
#pragma unroll
    for (int k = 0; k < 7; k++) {
        const u16* rec = Cb + (size_t)i0[k] * 64;
        rlo[k] = __builtin_bit_cast(s16x8, *(const u16x8*)(rec + q * 8));
        rhi[k] = __builtin_bit_cast(s16x8, *(const u16x8*)(rec + 32 + q * 8));
    }
    f4 acc0 = {0.f, 0.f, 0.f, 0.f};
    f4 acc1 = {0.f, 0.f, 0.f, 0.f};
#pragma unroll
    for (int k = 0; k < 7; k++) {
        acc0 = mfma16(wfv[(k * 4 + 0) * 64 + lane], rlo[k], acc0);
        acc1 = mfma16(wfv[(k * 4 + 1) * 64 + lane], rlo[k], acc1);
        acc0 = mfma16(wfv[(k * 4 + 2) * 64 + lane], rhi[k], acc0);
        acc1 = mfma16(wfv[(k * 4 + 3) * 64 + lane], rhi[k], acc1);
    }
    // fused stats: reduce over the 16 particles (p) per channel, f32 pre-rounding
    float s[8], t[8];
#pragma unroll
    for (int r = 0; r < 4; r++) {
        s[r] = acc0[r];     t[r] = acc0[r] * acc0[r];
        s[4 + r] = acc1[r]; t[4 + r] = acc1[r] * acc1[r];
    }
#pragma unroll
    for (int m = 1; m < 16; m <<= 1) {
#pragma unroll
        for (int j = 0; j < 8; j++) {
            s[j] += __shfl_xor(s[j], m);
            t[j] += __shfl_xor(t[j], m);
        }
    }
    if (p == 0) {
#pragma unroll
        for (int r = 0; r < 4; r++) {
            atomicAdd(&sst[(q * 4 + r) * 2],       s[r]);
            atomicAdd(&sst[(q * 4 + r) * 2 + 1],   t[r]);
            atomicAdd(&sst[(16 + q * 4 + r) * 2],     s[4 + r]);
            atomicAdd(&sst[(16 + q * 4 + r) * 2 + 1], t[4 + r]);
        }
    }
    // D: col = lane&15 = particle, row = 4*q + r = output channel
    u16x4 v0, v1;
#pragma unroll
    for (int r = 0; r < 4; r++) { v0[r] = f2b(acc0[r]); v1[r] = f2b(acc1[r]); }
    u16* out = h1 + ((size_t)b * NF + n) * CH + q * 4;
    __builtin_nontemporal_store(v0, (u16x4*)out);
    __builtin_nontemporal_store(v1, (u16x4*)(out + 16));
    __syncthreads();
    if (tid < 64) atomicAdd(&stats1[(size_t)(b * 64 + tid) * 32], sst[tid]);
}

// ---------------- conv2: gather-GEMM, fin1+norm1+relu fused, f32 out ------------
// GN-1 finalize per-lane in registers; f32 output stores non-temporal (205 MB
// stream was evicting the h1 gather pool from L3).
__global__ __launch_bounds__(512) void k_conv2(
    const u16* __restrict__ x, const u16* __restrict__ wfg,
    const int* __restrict__ nbr, const float* __restrict__ stats1,
    const float* __restrict__ g1, const float* __restrict__ b1,
    float* __restrict__ out, float* __restrict__ stats2)
{
    __shared__ u16 wf[7 * 2 * 512];   // 14 KB shared by 8 waves
    __shared__ float sst[64];
    int tid = threadIdx.x, b = blockIdx.y;
    if (tid < 64) sst[tid] = 0.f;
    const f4* wsrc = (const f4*)wfg;
    f4* wdst = (f4*)wf;
    for (int i = tid; i < 896; i += 512) wdst[i] = wsrc[i];
    __syncthreads();
    const s16x8* wfv = (const s16x8*)wf;
    int lane = tid & 63, wave = tid >> 6;
    int p = lane & 15, q = lane >> 4;
    int n = blockIdx.x * 128 + wave * 16 + p;
    const u16* Xb = x + (size_t)b * NF * CH;
    const int* nbb = nbr + ((size_t)b * NF + n) * 7;
    int i0[7];
#pragma unroll
    for (int k = 0; k < 7; k++) i0[k] = __builtin_nontemporal_load(&nbb[k]);
    // per-lane GN-1 finalize for this lane's 8 channels (L2-broadcast loads)
    float sc[8], sh[8];
#pragma unroll
    for (int j = 0; j < 8; j++) {
        int ch = q * 8 + j;
        float sum = stats1[(size_t)(b * 64 + ch * 2) * 32];
        float sq  = stats1[(size_t)(b * 64 + ch * 2 + 1) * 32];
        float mean = sum * (1.f / NF);
        float var = sq * (1.f / NF) - mean * mean;
        float s = rsqrtf(var + EPS) * g1[ch];
        sc[j] = s;
        sh[j] = b1[ch] - mean * s;
    }
    u16x8 raw[7];
#pragma unroll
    for (int k = 0; k < 7; k++)
        raw[k] = *(const u16x8*)(Xb + (size_t)i0[k] * CH + q * 8);
    f4 acc0 = {0.f, 0.f, 0.f, 0.f};
    f4 acc1 = {0.f, 0.f, 0.f, 0.f};
#pragma unroll
    for (int k = 0; k < 7; k++) {
        u16x8 nv;
#pragma unroll
        for (int j = 0; j < 8; j++)
            nv[j] = f2b(fmaxf(fmaf(b2f(raw[k][j]), sc[j], sh[j]), 0.f));
        s16x8 a = __builtin_bit_cast(s16x8, nv);
        acc0 = mfma16(wfv[(k * 2 + 0) * 64 + lane], a, acc0);
        acc1 = mfma16(wfv[(k * 2 + 1) * 64 + lane], a, acc1);
    }
    // fused stats2 on raw f32 conv output
    float s[8], t[8];
#pragma unroll
    for (int r = 0; r < 4; r++) {
        s[r] = acc0[r];     t[r] = acc0[r] * acc0[r];
        s[4 + r] = acc1[r]; t[4 + r] = acc1[r] * acc1[r];
    }
#pragma unroll
    for (int m = 1; m < 16; m <<= 1) {
#pragma unroll
        for (int j = 0; j < 8; j++) {
            s[j] += __shfl_xor(s[j], m);
            t[j] += __shfl_xor(t[j], m);
        }
    }
    if (p == 0) {
#pragma unroll
        for (int r = 0; r < 4; r++) {
            atomicAdd(&sst[(q * 4 + r) * 2],       s[r]);
            atomicAdd(&sst[(q * 4 + r) * 2 + 1],   t[r]);
            atomicAdd(&sst[(16 + q * 4 + r) * 2],     s[4 + r]);
            atomicAdd(&sst[(16 + q * 4 + r) * 2 + 1], t[4 + r]);
        }
    }
    // f32 transposed store: out[b][ch][n], non-temporal
    float* ob = out + (size_t)b * CH * NF + n;
#pragma unroll
    for (int r = 0; r < 4; r++) {
        __builtin_nontemporal_store(acc0[r], &ob[(size_t)(q * 4 + r) * NF]);
        __builtin_nontemporal_store(acc1[r], &ob[(size_t)(16 + q * 4 + r) * NF]);
    }
    __syncthreads();
    if (tid < 64) atomicAdd(&stats2[(size_t)(b * 64 + tid) * 32], sst[tid]);
}

// ---------------- in-place fin2+normalize+relu on f32 [B][32][NF] ---------------
__global__ __launch_bounds__(256) void k_norm2c(
    float* __restrict__ h, const float* __restrict__ stats2,
    const float* __restrict__ g2, const float* __restrict__ b2)
{
    const int total = BB * CH * (NF / 4);   // 6,400,000 f4 elements
    for (int i4 = blockIdx.x * 256 + threadIdx.x; i4 < total; i4 += gridDim.x * 256) {
        int cf = i4 / (NF / 4);              // 0..63 = b*32 + c
        int o = cf & 31;
        float sum = stats2[(size_t)(cf * 2) * 32];
        float sq  = stats2[(size_t)(cf * 2 + 1) * 32];
        float mean = sum * (1.f / NF);
        float var = sq * (1.f / NF) - mean * mean;
        float sc = rsqrtf(var + EPS) * g2[o];
        float sh = b2[o] - mean * sc;
        f4 v = __builtin_nontemporal_load(&((f4*)h)[i4]);
#pragma unroll
        for (int j = 0; j < 4; j++) v[j] = fmaxf(fmaf(v[j], sc, sh), 0.f);
        __builtin_nontemporal_store(v, &((f4*)h)[i4]);
    }
}

extern "C" void kernel_launch(void* const* d_in, const int* in_sizes, int n_in,
                              void* d_out, int out_size, void* d_ws, size_t ws_size,
                              hipStream_t stream)
{
    const float* x1 = (const float*)d_in[0];
    const float* x2 = (const float*)d_in[1];
    const float* wr = (const float*)d_in[2];
    const float* gA = (const float*)d_in[3];
    const float* bA = (const float*)d_in[4];
    const float* w1 = (const float*)d_in[5];
    const float* g1 = (const float*)d_in[6];
    const float* b1 = (const float*)d_in[7];
    const float* w2 = (const float*)d_in[8];
    const float* g2 = (const float*)d_in[9];
    const float* b2 = (const float*)d_in[10];
    const int* sidx = (const int*)d_in[11];
    const int* uidx = (const int*)d_in[12];
    const int* nbr  = (const int*)d_in[13];

    // comb [B][NF][64] bf16 = 102.4 MB lives in d_out (dead before conv2 writes
    // f32 output there). ws (~59.5 MB): h1 51.2 | y 8.19 | stats | wf tables.
    char* ws = (char*)d_ws;
    u16* h1      = (u16*)ws;                            // [B][NF][32] bf16
    u16* y       = (u16*)(ws + 51200000);               // [B][SVOX][32] bf16
    float* stats = (float*)(ws + 59392000);             // 3 x 16 KB padded accumulators
    float* statsA = stats;
    float* stats1 = (float*)(ws + 59392000 + 16384);
    float* stats2 = (float*)(ws + 59392000 + 32768);
    u16* wf1g = (u16*)(ws + 59392000 + 49152);          // 28672 B
    u16* wf2g = (u16*)(ws + 59392000 + 49152 + 28672);  // 14336 B
    u16* comb = (u16*)d_out;

    k_prep<<<48, 256, 0, stream>>>(w1, w2, stats, wf1g, wf2g);
    k_reduce<<<dim3(125, BB), 256, 0, stream>>>(x1, wr, y, statsA);
    k_build<<<dim3(1024, BB), 256, 0, stream>>>(x2, y, statsA, gA, bA, sidx, uidx, comb);
    k_conv1<<<dim3(3125, BB), 512, 0, stream>>>(comb, wf1g, nbr, h1, stats1);
    k_conv2<<<dim3(3125, BB), 512, 0, stream>>>(h1, wf2g, nbr, stats1, g1, b1, (float*)d_out, stats2);
    k_norm2c<<<2048, 256, 0, stream>>>((float*)d_out, stats2, g2, b2);
}